// Round 18
// baseline (222.812 us; speedup 1.0000x reference)
//
#include <hip/hip_runtime.h>

#define IN_DIM 64
#define HID 64
#define HEADS 4
#define DD 256      // HID*HEADS
#define ENC_H 512
#define DUEL_H 128
#define NEG_SLOPE 0.2f
#define WCAP 8192   // max |W| slots
#define ECAP 64     // max edges per W node (Poisson(16)+self; max deg ~45)

typedef _Float16 f16;
typedef __attribute__((ext_vector_type(2))) _Float16 f16x2;
typedef __attribute__((ext_vector_type(4))) _Float16 f16x4;
typedef __attribute__((ext_vector_type(8))) _Float16 f16x8;
typedef __attribute__((ext_vector_type(4))) float f32x4;

__device__ __forceinline__ f16x2 u2h(unsigned u) {
    union { unsigned u; f16x2 h; } c; c.u = u; return c.h;
}
__device__ __forceinline__ unsigned h2u(f16x2 h) {
    union { unsigned u; f16x2 h; } c; c.h = h; return c.u;
}

// ---------------- fused prep: cast x, transpose+cast weights, zero flags ----------------
// zeros[] = s0f(N) | inW(N) | wcnt(16), zeroed as one segment.

__global__ void prep_all(
    const float4* __restrict__ x, f16x4* __restrict__ x16, int nx4,
    const float* __restrict__ w1, const float* __restrict__ w2,
    const float* __restrict__ wl1, const float* __restrict__ wr1,
    const float* __restrict__ wl2, const float* __restrict__ wr2,
    f16* __restrict__ w1t, f16* __restrict__ w2t,
    f16* __restrict__ wcat1, f16* __restrict__ wcat2,
    f16* __restrict__ wr2nt,
    int* __restrict__ zeros, int nz) {
    int i = blockIdx.x * blockDim.x + threadIdx.x;
    if (i < nx4) {
        float4 v = x[i];
        f16x4 o = {(f16)v.x, (f16)v.y, (f16)v.z, (f16)v.w};
        x16[i] = o;
        return;
    }
    i -= nx4;
    if (i < 229376) {
        if (i < 32768) {                       // w1 [64][512] -> w1t [512][64]
            int k = i >> 9, n = i & 511;
            w1t[n * 64 + k] = (f16)w1[i];
        } else if (i < 65536) {                // w2 [512][64] -> w2t [64][512]
            int j = i - 32768; int k = j >> 6, n = j & 63;
            w2t[n * 512 + k] = (f16)w2[j];
        } else if (i < 81920) {                // wl1 [64][256] -> wcat1[0..256)[64]
            int j = i - 65536; int k = j >> 8, n = j & 255;
            wcat1[n * 64 + k] = (f16)wl1[j];
        } else if (i < 98304) {                // wr1 -> wcat1[256..512)[64]
            int j = i - 81920; int k = j >> 8, n = j & 255;
            wcat1[(256 + n) * 64 + k] = (f16)wr1[j];
        } else if (i < 163840) {               // wl2 [256][256] -> wcat2[0..256)[256]
            int j = i - 98304; int k = j >> 8, n = j & 255;
            wcat2[n * 256 + k] = (f16)wl2[j];
        } else {                               // wr2 [256][256] -> wr2nt (straight cast)
            int j = i - 163840;
            wr2nt[j] = (f16)wr2[j];
        }
        return;
    }
    i -= 229376;
    if (i < nz) zeros[i] = 0;
}

// ---------------- GEMM body (B-slab-resident fp16 MFMA, BM=64) ----------------

template <int K, int BN>
struct GemmCfg {
    static constexpr int SB = K + 8;
    static constexpr int CE = BN / 2 + 8;
    static constexpr int SLABSZ = BN * SB;
    static constexpr int EPISZ = 4 * 32 * CE;
    static constexpr int SMEMSZ = SLABSZ > EPISZ ? SLABSZ : EPISZ;   // in f16
};

template <int K, int BN>
__device__ __forceinline__ void gemm_body(
    int bx, int by, f16* __restrict__ smem,
    const f16* __restrict__ A, const f16* __restrict__ Bt,
    const float* __restrict__ biasA, const float* __restrict__ biasB, int NS,
    int M, int relu,
    f16* __restrict__ C1, f16* __restrict__ C2) {
    constexpr int KS = K / 32;
    constexpr int PF = (KS < 8) ? KS : 8;
    constexpr int COLW = BN / 2;
    constexpr int NT = COLW / 16;
    constexpr int SB = GemmCfg<K, BN>::SB;
    constexpr int CE = GemmCfg<K, BN>::CE;

    f16* Bs = smem;
    int tid = threadIdx.x;
    int wave = tid >> 6, lane = tid & 63;
    int quad = lane >> 4, l16 = lane & 15;
    int wr = wave >> 1, wc = wave & 1;
    int row0 = by * 64;
    int col0 = bx * BN;

    constexpr int NCH = BN * K / 8;
#pragma unroll
    for (int i = 0; i < NCH / 256; ++i) {
        int c = tid + i * 256;
        int r = c / (K / 8), ko = (c % (K / 8)) * 8;
        uint4 v = *(const uint4*)&Bt[(size_t)(col0 + r) * K + ko];
        *(uint4*)&Bs[r * SB + ko] = v;
    }
    __syncthreads();

    const f16* Aptr[2];
#pragma unroll
    for (int mt = 0; mt < 2; ++mt) {
        int arow = row0 + wr * 32 + mt * 16 + l16;
        if (arow >= M) arow = M - 1;
        Aptr[mt] = &A[(size_t)arow * K + quad * 8];
    }

    f32x4 acc[2][NT];
#pragma unroll
    for (int mt = 0; mt < 2; ++mt)
#pragma unroll
        for (int j = 0; j < NT; ++j) acc[mt][j] = (f32x4){0.f, 0.f, 0.f, 0.f};

    f16x8 afb[2][PF];
#pragma unroll
    for (int mt = 0; mt < 2; ++mt)
#pragma unroll
        for (int i = 0; i < PF; ++i)
            afb[mt][i] = *(const f16x8*)&Aptr[mt][i * 32];

#pragma unroll
    for (int s = 0; s < KS; ++s) {
        f16x8 af0 = afb[0][s % PF], af1 = afb[1][s % PF];
        if (s + PF < KS) {
            afb[0][s % PF] = *(const f16x8*)&Aptr[0][(s + PF) * 32];
            afb[1][s % PF] = *(const f16x8*)&Aptr[1][(s + PF) * 32];
        }
        const f16* bbase = &Bs[(size_t)(wc * COLW) * SB + s * 32 + quad * 8];
#pragma unroll
        for (int nt = 0; nt < NT; ++nt) {
            f16x8 bf = *(const f16x8*)&bbase[(nt * 16 + l16) * SB];
            acc[0][nt] = __builtin_amdgcn_mfma_f32_16x16x32_f16(af0, bf, acc[0][nt], 0, 0, 0);
            acc[1][nt] = __builtin_amdgcn_mfma_f32_16x16x32_f16(af1, bf, acc[1][nt], 0, 0, 0);
        }
    }

    __syncthreads();
    f16* ep = &smem[wave * 32 * CE];
#pragma unroll
    for (int mt = 0; mt < 2; ++mt)
#pragma unroll
        for (int nt = 0; nt < NT; ++nt) {
            int gcol = col0 + wc * COLW + nt * 16 + l16;
            float bb = (gcol < NS) ? biasA[gcol] : biasB[gcol - NS];
#pragma unroll
            for (int r = 0; r < 4; ++r) {
                float v = acc[mt][nt][r] + bb;
                if (relu) v = fmaxf(v, 0.f);
                ep[(mt * 16 + quad * 4 + r) * CE + nt * 16 + l16] = (f16)v;
            }
        }
    constexpr int CPR = COLW / 8;
    constexpr int NPASS = (32 * CPR) / 64;
#pragma unroll
    for (int i = 0; i < NPASS; ++i) {
        int u = lane + i * 64;
        int row = u / CPR, seg = u % CPR;
        uint4 v = *(const uint4*)&ep[row * CE + seg * 8];
        int grow = row0 + wr * 32 + row;
        int gcol = col0 + wc * COLW + seg * 8;
        if (grow < M) {
            if (gcol < NS) *(uint4*)&C1[(size_t)grow * NS + gcol] = v;
            else           *(uint4*)&C2[(size_t)grow * NS + (gcol - NS)] = v;
        }
    }
}

// ---------------- worklist + edge-list build ----------------

__device__ __forceinline__ void wappend(int src, int* __restrict__ inW,
                                        int* __restrict__ wcnt,
                                        int* __restrict__ wlist,
                                        int* __restrict__ mapv,
                                        int* __restrict__ w_edges,
                                        int* __restrict__ ecnt) {
    if (atomicExch(&inW[src], 1) == 0) {
        int c = atomicAdd(wcnt, 1);
        if (c < WCAP) {
            wlist[c] = src;
            mapv[src] = c;
            w_edges[c * ECAP] = src;   // self-loop seed
            ecnt[c] = 1;
        }
    }
}

// ---------------- merged dispatches ----------------
// enc1 + S0-mark (last block): both depend only on prep_all.
__global__ __launch_bounds__(256) void enc1_s0_kernel(
    const f16* __restrict__ A, const f16* __restrict__ Bt,
    const float* __restrict__ bias, int M, f16* __restrict__ C, int gemmBlocks,
    const int* __restrict__ indices, int B,
    int* __restrict__ s0f, int* __restrict__ inW, int* __restrict__ wcnt,
    int* __restrict__ wlist, int* __restrict__ mapv,
    int* __restrict__ w_edges, int* __restrict__ ecnt) {
    __shared__ __align__(16) f16 smem[GemmCfg<64, 128>::SMEMSZ];
    int bid = blockIdx.x;
    if (bid >= gemmBlocks) {                   // S0 mark + seed worklist
        int t = threadIdx.x;
        if (t < B) {
            int src = indices[t];
            s0f[src] = 1;
            wappend(src, inW, wcnt, wlist, mapv, w_edges, ecnt);
        }
        return;
    }
    gemm_body<64, 128>(bid & 3, bid >> 2, smem, A, Bt, bias, bias, 512, M, 1, C, C);
}

// enc2 + W-scan: enc2 needs enc1; W-scan needs S0 marks.
__global__ __launch_bounds__(256) void enc2_wscan_kernel(
    const f16* __restrict__ A, const f16* __restrict__ Bt,
    const float* __restrict__ bias, int M, f16* __restrict__ C, int gemmBlocks,
    const int* __restrict__ ei, int E,
    const int* __restrict__ s0f, int* __restrict__ inW, int* __restrict__ wcnt,
    int* __restrict__ wlist, int* __restrict__ mapv,
    int* __restrict__ w_edges, int* __restrict__ ecnt) {
    __shared__ __align__(16) f16 smem[GemmCfg<512, 64>::SMEMSZ];
    int bid = blockIdx.x;
    if (bid < gemmBlocks) {
        gemm_body<512, 64>(0, bid, smem, A, Bt, bias, bias, 64, M, 1, C, C);
    } else {                                   // W scan over original E edges
        int e = (bid - gemmBlocks) * 256 + threadIdx.x;
        if (e < E) {
            int dst = ei[E + e];
            if (s0f[dst])
                wappend(ei[e], inW, wcnt, wlist, mapv, w_edges, ecnt);
        }
    }
}

// conv1t + W edge-list build: conv1t needs enc2; ebuild needs inW/mapv (complete).
__global__ __launch_bounds__(256) void conv1t_ebuild_kernel(
    const f16* __restrict__ A, const f16* __restrict__ Bt,
    const float* __restrict__ biasA, const float* __restrict__ biasB, int M,
    f16* __restrict__ C1, f16* __restrict__ C2, int gemmBlocks,
    const int* __restrict__ ei, int E,
    const int* __restrict__ inW, const int* __restrict__ mapv,
    int* __restrict__ w_edges, int* __restrict__ ecnt) {
    __shared__ __align__(16) f16 smem[GemmCfg<64, 128>::SMEMSZ];
    int bid = blockIdx.x;
    if (bid < gemmBlocks) {
        gemm_body<64, 128>(bid & 3, bid >> 2, smem, A, Bt, biasA, biasB, DD, M, 0, C1, C2);
    } else {
        int e = (bid - gemmBlocks) * 256 + threadIdx.x;
        if (e < E) {
            int dst = ei[E + e];
            if (inW[dst]) {
                int c = mapv[dst];
                int pos = atomicAdd(&ecnt[c], 1);
                if (pos < ECAP) w_edges[c * ECAP + pos] = ei[e];
            }
        }
    }
}

// ---------------- fused GATv2 layer 1 + conv2t xl: 1 W-node/wave ----------------
// Each wave computes hC1[node] for its W slot, then the BLOCK cooperatively
// computes the conv2 xl row for each of its 4 waves' nodes (xl2[w] depends
// only on this wave's own hC1 row -> legal intra-block fusion). Uniform
// barriers: inactive waves participate with L=0 / guarded writes.

__global__ __launch_bounds__(256) void gat1_conv2t_kernel(
    const uint4* __restrict__ xl, const uint4* __restrict__ xr,
    const float4* __restrict__ att,
    const int* __restrict__ wlist, const int* __restrict__ wcnt,
    const int* __restrict__ w_edges, const int* __restrict__ ecnt,
    const float4* __restrict__ bias, uint4* __restrict__ h16,
    const f16* __restrict__ wcat2, const float* __restrict__ bl2,
    f16* __restrict__ xl2) {
    __shared__ f16 rowbuf[4][264];             // per-wave hC1 row (+pad)
    int wc0 = wcnt[0];
    if (wc0 > WCAP) wc0 = WCAP;
    int tid = threadIdx.x;
    int w = (blockIdx.x * blockDim.x + tid) >> 6;
    int lane = tid & 63;
    int wave = tid >> 6;
    int half = lane >> 5, l32 = lane & 31;
    bool active = (w < wc0);
    int wi = active ? w : 0;
    int node = wlist[wi];
    int L = active ? ecnt[wi] : 0;
    if (L > ECAP) L = ECAP;
    const int* elist = &w_edges[wi * ECAP];
    uint4 xrw = xr[(size_t)node * 32 + l32];
    f16x2 xr0 = u2h(xrw.x), xr1 = u2h(xrw.y), xr2 = u2h(xrw.z), xr3 = u2h(xrw.w);
    float4 awA = att[l32 * 2], awB = att[l32 * 2 + 1];
    f16x2 a6[4] = {{(f16)(0.6f * awA.x), (f16)(0.6f * awA.y)},
                   {(f16)(0.6f * awA.z), (f16)(0.6f * awA.w)},
                   {(f16)(0.6f * awB.x), (f16)(0.6f * awB.y)},
                   {(f16)(0.6f * awB.z), (f16)(0.6f * awB.w)}};
    f16x2 a4[4] = {{(f16)(0.4f * awA.x), (f16)(0.4f * awA.y)},
                   {(f16)(0.4f * awA.z), (f16)(0.4f * awA.w)},
                   {(f16)(0.4f * awB.x), (f16)(0.4f * awB.y)},
                   {(f16)(0.4f * awB.z), (f16)(0.4f * awB.w)}};
    float denom = 0.f;
    float acc0 = 0.f, acc1 = 0.f, acc2 = 0.f, acc3 = 0.f;
    float acc4 = 0.f, acc5 = 0.f, acc6 = 0.f, acc7 = 0.f;

    auto edge_dot = [&](uint4 raw) -> float {
        f16x2 t0 = u2h(raw.x) + xr0, t1 = u2h(raw.y) + xr1;
        f16x2 t2 = u2h(raw.z) + xr2, t3 = u2h(raw.w) + xr3;
        float d = __builtin_amdgcn_fdot2(t0, a6[0], 0.f, false);
        d = __builtin_amdgcn_fdot2(u2h(h2u(t0) & 0x7FFF7FFFu), a4[0], d, false);
        d = __builtin_amdgcn_fdot2(t1, a6[1], d, false);
        d = __builtin_amdgcn_fdot2(u2h(h2u(t1) & 0x7FFF7FFFu), a4[1], d, false);
        d = __builtin_amdgcn_fdot2(t2, a6[2], d, false);
        d = __builtin_amdgcn_fdot2(u2h(h2u(t2) & 0x7FFF7FFFu), a4[2], d, false);
        d = __builtin_amdgcn_fdot2(t3, a6[3], d, false);
        d = __builtin_amdgcn_fdot2(u2h(h2u(t3) & 0x7FFF7FFFu), a4[3], d, false);
        return d;
    };
    auto accum = [&](uint4 raw, float ee) {
        f16x2 v0 = u2h(raw.x), v1 = u2h(raw.y), v2 = u2h(raw.z), v3 = u2h(raw.w);
        acc0 = fmaf(ee, (float)v0.x, acc0); acc1 = fmaf(ee, (float)v0.y, acc1);
        acc2 = fmaf(ee, (float)v1.x, acc2); acc3 = fmaf(ee, (float)v1.y, acc3);
        acc4 = fmaf(ee, (float)v2.x, acc4); acc5 = fmaf(ee, (float)v2.y, acc5);
        acc6 = fmaf(ee, (float)v3.x, acc6); acc7 = fmaf(ee, (float)v3.y, acc7);
    };

    int p = half;   // this half's first edge; halves interleave stride 2
    for (; p + 6 < L; p += 8) {
        uint4 raw[4];
#pragma unroll
        for (int j = 0; j < 4; ++j)
            raw[j] = xl[(size_t)elist[p + j * 2] * 32 + l32];
        float sc[4];
#pragma unroll
        for (int j = 0; j < 4; ++j) sc[j] = edge_dot(raw[j]);
#pragma unroll
        for (int j = 0; j < 4; ++j) sc[j] += __shfl_xor(sc[j], 1);
#pragma unroll
        for (int j = 0; j < 4; ++j) sc[j] += __shfl_xor(sc[j], 2);
#pragma unroll
        for (int j = 0; j < 4; ++j) sc[j] += __shfl_xor(sc[j], 4);
#pragma unroll
        for (int j = 0; j < 4; ++j) {
            float ee = __expf(sc[j]);
            denom += ee;
            accum(raw[j], ee);
        }
    }
    for (; p < L; p += 2) {
        uint4 raw = xl[(size_t)elist[p] * 32 + l32];
        float d = edge_dot(raw);
        d += __shfl_xor(d, 1);
        d += __shfl_xor(d, 2);
        d += __shfl_xor(d, 4);
        float ee = __expf(d);
        denom += ee;
        accum(raw, ee);
    }
    // combine halves (both halves end with the full sums)
    denom += __shfl_xor(denom, 32);
    acc0 += __shfl_xor(acc0, 32); acc1 += __shfl_xor(acc1, 32);
    acc2 += __shfl_xor(acc2, 32); acc3 += __shfl_xor(acc3, 32);
    acc4 += __shfl_xor(acc4, 32); acc5 += __shfl_xor(acc5, 32);
    acc6 += __shfl_xor(acc6, 32); acc7 += __shfl_xor(acc7, 32);

    float inv = 1.f / (denom + 1e-16f);
    float4 bbA = bias[l32 * 2], bbB = bias[l32 * 2 + 1];
    float o0 = fmaxf(fmaf(acc0, inv, bbA.x), 0.f);
    float o1 = fmaxf(fmaf(acc1, inv, bbA.y), 0.f);
    float o2 = fmaxf(fmaf(acc2, inv, bbA.z), 0.f);
    float o3 = fmaxf(fmaf(acc3, inv, bbA.w), 0.f);
    float o4 = fmaxf(fmaf(acc4, inv, bbB.x), 0.f);
    float o5 = fmaxf(fmaf(acc5, inv, bbB.y), 0.f);
    float o6 = fmaxf(fmaf(acc6, inv, bbB.z), 0.f);
    float o7 = fmaxf(fmaf(acc7, inv, bbB.w), 0.f);
    f16x2 h0 = {(f16)o0, (f16)o1}, h1 = {(f16)o2, (f16)o3};
    f16x2 h2 = {(f16)o4, (f16)o5}, h3 = {(f16)o6, (f16)o7};
    if (half == 0) {
        // stash row for the conv2t matvec (f16, matching hC1 rounding)
        f16* rb = &rowbuf[wave][l32 * 8];
        rb[0] = h0.x; rb[1] = h0.y; rb[2] = h1.x; rb[3] = h1.y;
        rb[4] = h2.x; rb[5] = h2.y; rb[6] = h3.x; rb[7] = h3.y;
        if (active) {
            uint4 outw = make_uint4(h2u(h0), h2u(h1), h2u(h2), h2u(h3));
            h16[(size_t)node * 32 + l32] = outw;
        }
    }
    __syncthreads();

    // ---- conv2t xl rows for this block's 4 waves: xl2[w] = row @ wl2 + bl2 ----
    // thread t = output col; one weight chunk read serves all 4 rows.
    int wbase = blockIdx.x * 4;
    bool wact[4];
#pragma unroll
    for (int v = 0; v < 4; ++v) wact[v] = (wbase + v) < wc0;
    {
        int c = tid;          // 0..255
        float a0c = 0.f, a1c = 0.f, a2c = 0.f, a3c = 0.f;
        const f16* wcol = &wcat2[(size_t)c * 256];
#pragma unroll 4
        for (int k = 0; k < 256; k += 8) {
            f16x8 wv = *(const f16x8*)&wcol[k];
#pragma unroll
            for (int j = 0; j < 8; ++j) {
                float wj = (float)wv[j];
                a0c = fmaf((float)rowbuf[0][k + j], wj, a0c);
                a1c = fmaf((float)rowbuf[1][k + j], wj, a1c);
                a2c = fmaf((float)rowbuf[2][k + j], wj, a2c);
                a3c = fmaf((float)rowbuf[3][k + j], wj, a3c);
            }
        }
        float bb = bl2[c];
        if (wact[0]) xl2[(size_t)(wbase + 0) * DD + c] = (f16)(a0c + bb);
        if (wact[1]) xl2[(size_t)(wbase + 1) * DD + c] = (f16)(a1c + bb);
        if (wact[2]) xl2[(size_t)(wbase + 2) * DD + c] = (f16)(a2c + bb);
        if (wact[3]) xl2[(size_t)(wbase + 3) * DD + c] = (f16)(a3c + bb);
    }
}

// ---------------- fused GAT2 (indexed) + dueling head, 1024 threads / batch elem ----------------
// xl rows are COMPACT; node's edge list at mapv[node].

__global__ __launch_bounds__(1024) void gat2_head_kernel(
    const uint4* __restrict__ xl, const f16* __restrict__ hC1,
    const f16* __restrict__ wr2nt, const float* __restrict__ br2,
    const float4* __restrict__ att,
    const int* __restrict__ indices, const int* __restrict__ mapv,
    const int* __restrict__ w_edges, const int* __restrict__ ecnt,
    const float* __restrict__ bias2, const f16* __restrict__ hE16,
    const float* __restrict__ qw1, const float* __restrict__ qb1,
    const float* __restrict__ qw2, const float* __restrict__ qb2,
    const float* __restrict__ vw1, const float* __restrict__ vb1,
    const float* __restrict__ vw2, const float* __restrict__ vb2,
    float* __restrict__ out) {
    __shared__ float feat[576];
    __shared__ float xrs[256];
    __shared__ float partial[4][256];
    __shared__ float pden[16][32];
    __shared__ float pacc[16][32][8];
    __shared__ float red[384];
    int b = blockIdx.x;
    int t = threadIdx.x;
    int wave = t >> 6, lane = t & 63;
    int half = lane >> 5, l32 = lane & 31;
    int node = indices[b];

    // ---- phase 0: feat[0..320) ----
    if (t < 320) {
        feat[t] = (t < 64) ? (float)hE16[(size_t)node * 64 + t]
                           : (float)hC1[(size_t)node * 256 + t - 64];
    }
    __syncthreads();

    // ---- phase 1: xr (coalesced, k-quartered) ----
    {
        int o = t & 255, kq = t >> 8;
        const f16* w = &wr2nt[(size_t)(kq * 64) * 256 + o];
        const float* f = &feat[64 + kq * 64];
        float a0 = 0.f, a1 = 0.f;
#pragma unroll
        for (int k = 0; k < 64; k += 2) {
            a0 = fmaf(f[k],     (float)w[(size_t)k * 256],       a0);
            a1 = fmaf(f[k + 1], (float)w[(size_t)(k + 1) * 256], a1);
        }
        partial[kq][o] = a0 + a1;
    }
    __syncthreads();
    if (t < 256)
        xrs[t] = partial[0][t] + partial[1][t] + partial[2][t] + partial[3][t] + br2[t];
    __syncthreads();

    f16x2 xr0 = {(f16)xrs[l32 * 8 + 0], (f16)xrs[l32 * 8 + 1]};
    f16x2 xr1 = {(f16)xrs[l32 * 8 + 2], (f16)xrs[l32 * 8 + 3]};
    f16x2 xr2 = {(f16)xrs[l32 * 8 + 4], (f16)xrs[l32 * 8 + 5]};
    f16x2 xr3 = {(f16)xrs[l32 * 8 + 6], (f16)xrs[l32 * 8 + 7]};

    // ---- phase 2: GAT edge loop, 32-way slice split ----
    int cidx0 = mapv[node];
    int L = ecnt[cidx0];
    if (L > ECAP) L = ECAP;
    const int* elist = &w_edges[cidx0 * ECAP];
    float4 awA = att[l32 * 2], awB = att[l32 * 2 + 1];
    f16x2 a6[4] = {{(f16)(0.6f * awA.x), (f16)(0.6f * awA.y)},
                   {(f16)(0.6f * awA.z), (f16)(0.6f * awA.w)},
                   {(f16)(0.6f * awB.x), (f16)(0.6f * awB.y)},
                   {(f16)(0.6f * awB.z), (f16)(0.6f * awB.w)}};
    f16x2 a4[4] = {{(f16)(0.4f * awA.x), (f16)(0.4f * awA.y)},
                   {(f16)(0.4f * awA.z), (f16)(0.4f * awA.w)},
                   {(f16)(0.4f * awB.x), (f16)(0.4f * awB.y)},
                   {(f16)(0.4f * awB.z), (f16)(0.4f * awB.w)}};
    float denom = 0.f;
    float acc0 = 0.f, acc1 = 0.f, acc2 = 0.f, acc3 = 0.f;
    float acc4 = 0.f, acc5 = 0.f, acc6 = 0.f, acc7 = 0.f;

    auto edge_dot = [&](uint4 raw) -> float {
        f16x2 t0 = u2h(raw.x) + xr0, t1 = u2h(raw.y) + xr1;
        f16x2 t2 = u2h(raw.z) + xr2, t3 = u2h(raw.w) + xr3;
        float d = __builtin_amdgcn_fdot2(t0, a6[0], 0.f, false);
        d = __builtin_amdgcn_fdot2(u2h(h2u(t0) & 0x7FFF7FFFu), a4[0], d, false);
        d = __builtin_amdgcn_fdot2(t1, a6[1], d, false);
        d = __builtin_amdgcn_fdot2(u2h(h2u(t1) & 0x7FFF7FFFu), a4[1], d, false);
        d = __builtin_amdgcn_fdot2(t2, a6[2], d, false);
        d = __builtin_amdgcn_fdot2(u2h(h2u(t2) & 0x7FFF7FFFu), a4[2], d, false);
        d = __builtin_amdgcn_fdot2(t3, a6[3], d, false);
        d = __builtin_amdgcn_fdot2(u2h(h2u(t3) & 0x7FFF7FFFu), a4[3], d, false);
        return d;
    };
    auto accum = [&](uint4 raw, float ee) {
        f16x2 v0 = u2h(raw.x), v1 = u2h(raw.y), v2 = u2h(raw.z), v3 = u2h(raw.w);
        acc0 = fmaf(ee, (float)v0.x, acc0); acc1 = fmaf(ee, (float)v0.y, acc1);
        acc2 = fmaf(ee, (float)v1.x, acc2); acc3 = fmaf(ee, (float)v1.y, acc3);
        acc4 = fmaf(ee, (float)v2.x, acc4); acc5 = fmaf(ee, (float)v2.y, acc5);
        acc6 = fmaf(ee, (float)v3.x, acc6); acc7 = fmaf(ee, (float)v3.y, acc7);
    };

    for (int p = (wave << 1) + half; p < L; p += 32) {
        int cidx = mapv[elist[p]];
        uint4 raw = xl[(size_t)cidx * 32 + l32];
        float d = edge_dot(raw);
        d += __shfl_xor(d, 1);
        d += __shfl_xor(d, 2);
        d += __shfl_xor(d, 4);
        float ee = __expf(d);
        denom += ee;
        accum(raw, ee);
    }
    denom += __shfl_xor(denom, 32);
    acc0 += __shfl_xor(acc0, 32); acc1 += __shfl_xor(acc1, 32);
    acc2 += __shfl_xor(acc2, 32); acc3 += __shfl_xor(acc3, 32);
    acc4 += __shfl_xor(acc4, 32); acc5 += __shfl_xor(acc5, 32);
    acc6 += __shfl_xor(acc6, 32); acc7 += __shfl_xor(acc7, 32);
    if (half == 0) {
        pden[wave][l32] = denom;
        pacc[wave][l32][0] = acc0; pacc[wave][l32][1] = acc1;
        pacc[wave][l32][2] = acc2; pacc[wave][l32][3] = acc3;
        pacc[wave][l32][4] = acc4; pacc[wave][l32][5] = acc5;
        pacc[wave][l32][6] = acc6; pacc[wave][l32][7] = acc7;
    }
    __syncthreads();

    if (t < 256) {
        int lw = t >> 3, d = t & 7;
        float den = 0.f, a = 0.f;
#pragma unroll
        for (int w = 0; w < 16; ++w) { den += pden[w][lw]; a += pacc[w][lw][d]; }
        float inv = 1.f / (den + 1e-16f);
        feat[320 + t] = fmaxf(fmaf(a, inv, bias2[t]), 0.f);
    }
    __syncthreads();

    // ---- phase 3: dueling head, (o, k-quarter) decomposition ----
    {
        int o = t & 255, kq = t >> 8;
        int k0 = kq * 144;
        float a0 = 0.f, a1 = 0.f;
        if (o < 128) {
            const float* w = &qw1[(size_t)k0 * 128 + o];
            const float* f = &feat[k0];
#pragma unroll
            for (int k = 0; k < 144; k += 2) {
                a0 = fmaf(f[k],     w[(size_t)k * 128],       a0);
                a1 = fmaf(f[k + 1], w[(size_t)(k + 1) * 128], a1);
            }
        } else {
            const float* w = &vw1[(size_t)k0 * 128 + (o - 128)];
            const float* f = &feat[k0];
#pragma unroll
            for (int k = 0; k < 144; k += 2) {
                a0 = fmaf(f[k],     w[(size_t)k * 128],       a0);
                a1 = fmaf(f[k + 1], w[(size_t)(k + 1) * 128], a1);
            }
        }
        partial[kq][o] = a0 + a1;
    }
    __syncthreads();
    if (t < 256) {
        float s4 = partial[0][t] + partial[1][t] + partial[2][t] + partial[3][t];
        if (t < 128) {
            float aq = fmaxf(s4 + qb1[t], 0.f);
            red[t]       = aq * qw2[t * 2 + 0];
            red[128 + t] = aq * qw2[t * 2 + 1];
        } else {
            int tv = t - 128;
            float av = fmaxf(s4 + vb1[tv], 0.f);
            red[256 + tv] = av * vw2[tv];
        }
    }
    __syncthreads();
    for (int s2 = 64; s2 > 0; s2 >>= 1) {
        if (t < s2) {
            red[t] += red[t + s2];
            red[128 + t] += red[128 + t + s2];
            red[256 + t] += red[256 + t + s2];
        }
        __syncthreads();
    }
    if (t == 0) {
        float q0 = red[0] + qb2[0];
        float q1 = red[128] + qb2[1];
        float v  = red[256] + vb2[0];
        float mean = 0.5f * (q0 + q1);
        out[b * 2 + 0] = q0 - mean + v;
        out[b * 2 + 1] = q1 - mean + v;
    }
}

// ---------------- launch ----------------

extern "C" void kernel_launch(void* const* d_in, const int* in_sizes, int n_in,
                              void* d_out, int out_size, void* d_ws, size_t ws_size,
                              hipStream_t stream) {
    const float* x      = (const float*)d_in[0];
    const int*   ei     = (const int*)d_in[1];
    const int*   indices= (const int*)d_in[2];
    const float* enc_w1 = (const float*)d_in[3];
    const float* enc_b1 = (const float*)d_in[4];
    const float* enc_w2 = (const float*)d_in[5];
    const float* enc_b2 = (const float*)d_in[6];
    const float* wl1    = (const float*)d_in[7];
    const float* bl1    = (const float*)d_in[8];
    const float* wr1    = (const float*)d_in[9];
    const float* br1    = (const float*)d_in[10];
    const float* att1   = (const float*)d_in[11];
    const float* bias1  = (const float*)d_in[12];
    const float* wl2    = (const float*)d_in[13];
    const float* bl2    = (const float*)d_in[14];
    const float* wr2    = (const float*)d_in[15];
    const float* br2    = (const float*)d_in[16];
    const float* att2   = (const float*)d_in[17];
    const float* bias2  = (const float*)d_in[18];
    const float* qw1    = (const float*)d_in[19];
    const float* qb1    = (const float*)d_in[20];
    const float* qw2    = (const float*)d_in[21];
    const float* qb2    = (const float*)d_in[22];
    const float* vw1    = (const float*)d_in[23];
    const float* vb1    = (const float*)d_in[24];
    const float* vw2    = (const float*)d_in[25];
    const float* vb2    = (const float*)d_in[26];

    const int N = in_sizes[0] / IN_DIM;
    const int E = in_sizes[1] / 2;
    const int B = in_sizes[2];

    // ---- workspace arena ----
    char* wsb = (char*)d_ws;
    size_t off = 0;
    auto alloc = [&](size_t bytes) -> void* {
        void* p = wsb + off;
        off = (off + bytes + 255) & ~(size_t)255;
        return p;
    };
    f16* x16     = (f16*)alloc((size_t)N * 64 * 2);
    f16* h1_16   = (f16*)alloc((size_t)N * 512 * 2);
    f16* hE16    = (f16*)alloc((size_t)N * 64 * 2);
    f16* xl16    = (f16*)alloc((size_t)N * 256 * 2);
    f16* xr16    = (f16*)alloc((size_t)N * 256 * 2);
    f16* hC1_16  = (f16*)alloc((size_t)N * 256 * 2);
    f16* xl2c    = (f16*)alloc((size_t)WCAP * 256 * 2);
    f16* w1t     = (f16*)alloc((size_t)ENC_H * IN_DIM * 2);
    f16* w2t     = (f16*)alloc((size_t)HID * ENC_H * 2);
    f16* wcat1   = (f16*)alloc((size_t)512 * HID * 2);
    f16* wcat2   = (f16*)alloc((size_t)256 * DD * 2);
    f16* wr2nt   = (f16*)alloc((size_t)DD * DD * 2);
    int* zeros   = (int*)alloc((size_t)(2 * N + 16) * 4);
    int* s0f     = zeros;                 // N
    int* inW     = s0f + N;               // N
    int* wcnt    = inW + N;               // 16
    int* wlist   = (int*)alloc((size_t)WCAP * 4);
    int* mapv    = (int*)alloc((size_t)N * 4);
    int* ecnt    = (int*)alloc((size_t)WCAP * 4);
    int* w_edges = (int*)alloc((size_t)WCAP * ECAP * 4);

    // ---- D1: prep (casts, weight transposes, zero flags) ----
    int nx4 = N * 16;
    int nz = 2 * N + 16;
    int ntot = nx4 + 229376 + nz;
    prep_all<<<(ntot + 255) / 256, 256, 0, stream>>>(
        (const float4*)x, (f16x4*)x16, nx4,
        enc_w1, enc_w2, wl1, wr1, wl2, wr2,
        w1t, w2t, wcat1, wcat2, wr2nt, zeros, nz);

    int grows = (N + 63) / 64;          // 313
    int gemmB1 = 4 * grows;             // 1252
    int escanB = (E + 255) / 256;

    // ---- D2: enc1 + S0 mark/seed ----
    enc1_s0_kernel<<<gemmB1 + 1, 256, 0, stream>>>(
        x16, w1t, enc_b1, N, h1_16, gemmB1,
        indices, B, s0f, inW, wcnt, wlist, mapv, w_edges, ecnt);

    // ---- D3: enc2 + W scan ----
    enc2_wscan_kernel<<<grows + escanB, 256, 0, stream>>>(
        h1_16, w2t, enc_b2, N, hE16, grows,
        ei, E, s0f, inW, wcnt, wlist, mapv, w_edges, ecnt);

    // ---- D4: conv1 transform + W edge-list build ----
    conv1t_ebuild_kernel<<<gemmB1 + escanB, 256, 0, stream>>>(
        hE16, wcat1, bl1, br1, N, xl16, xr16, gemmB1,
        ei, E, inW, mapv, w_edges, ecnt);

    // ---- D5: GAT 1 over W + fused conv2t xl rows ----
    gat1_conv2t_kernel<<<(WCAP * 64) / 256, 256, 0, stream>>>(
        (const uint4*)xl16, (const uint4*)xr16, (const float4*)att1,
        wlist, wcnt, w_edges, ecnt, (const float4*)bias1, (uint4*)hC1_16,
        wcat2, bl2, xl2c);

    // ---- D6: GAT 2 (indexed) + dueling head, fused, 1024 threads ----
    gat2_head_kernel<<<B, 1024, 0, stream>>>(
        (const uint4*)xl2c, hC1_16, wr2nt, br2, (const float4*)att2,
        indices, mapv, w_edges, ecnt, bias2, hE16,
        qw1, qb1, qw2, qb2, vw1, vb1, vw2, vb2, (float*)d_out);
}

// Round 19
// 181.934 us; speedup vs baseline: 1.2247x; 1.2247x over previous
//
#include <hip/hip_runtime.h>

#define IN_DIM 64
#define HID 64
#define HEADS 4
#define DD 256      // HID*HEADS
#define ENC_H 512
#define DUEL_H 128
#define NEG_SLOPE 0.2f
#define WCAP 8192   // max |W| slots
#define ECAP 64     // max edges per W node (Poisson(16)+self; max deg ~45)

typedef _Float16 f16;
typedef __attribute__((ext_vector_type(2))) _Float16 f16x2;
typedef __attribute__((ext_vector_type(4))) _Float16 f16x4;
typedef __attribute__((ext_vector_type(8))) _Float16 f16x8;
typedef __attribute__((ext_vector_type(4))) float f32x4;

__device__ __forceinline__ f16x2 u2h(unsigned u) {
    union { unsigned u; f16x2 h; } c; c.u = u; return c.h;
}
__device__ __forceinline__ unsigned h2u(f16x2 h) {
    union { unsigned u; f16x2 h; } c; c.h = h; return c.u;
}

// ---------------- fused prep: cast x, transpose+cast weights, zero flags ----------------
// zeros[] = s0f(N) | inW(N) | wcnt(16), zeroed as one segment.

__global__ void prep_all(
    const float4* __restrict__ x, f16x4* __restrict__ x16, int nx4,
    const float* __restrict__ w1, const float* __restrict__ w2,
    const float* __restrict__ wl1, const float* __restrict__ wr1,
    const float* __restrict__ wl2, const float* __restrict__ wr2,
    f16* __restrict__ w1t, f16* __restrict__ w2t,
    f16* __restrict__ wcat1, f16* __restrict__ wcat2,
    f16* __restrict__ wr2nt,
    int* __restrict__ zeros, int nz) {
    int i = blockIdx.x * blockDim.x + threadIdx.x;
    if (i < nx4) {
        float4 v = x[i];
        f16x4 o = {(f16)v.x, (f16)v.y, (f16)v.z, (f16)v.w};
        x16[i] = o;
        return;
    }
    i -= nx4;
    if (i < 229376) {
        if (i < 32768) {                       // w1 [64][512] -> w1t [512][64]
            int k = i >> 9, n = i & 511;
            w1t[n * 64 + k] = (f16)w1[i];
        } else if (i < 65536) {                // w2 [512][64] -> w2t [64][512]
            int j = i - 32768; int k = j >> 6, n = j & 63;
            w2t[n * 512 + k] = (f16)w2[j];
        } else if (i < 81920) {                // wl1 [64][256] -> wcat1[0..256)[64]
            int j = i - 65536; int k = j >> 8, n = j & 255;
            wcat1[n * 64 + k] = (f16)wl1[j];
        } else if (i < 98304) {                // wr1 -> wcat1[256..512)[64]
            int j = i - 81920; int k = j >> 8, n = j & 255;
            wcat1[(256 + n) * 64 + k] = (f16)wr1[j];
        } else if (i < 163840) {               // wl2 [256][256] -> wcat2[0..256)[256]
            int j = i - 98304; int k = j >> 8, n = j & 255;
            wcat2[n * 256 + k] = (f16)wl2[j];
        } else {                               // wr2 [256][256] -> wr2nt (straight cast)
            int j = i - 163840;
            wr2nt[j] = (f16)wr2[j];
        }
        return;
    }
    i -= 229376;
    if (i < nz) zeros[i] = 0;
}

// ---------------- GEMM body (B-slab-resident fp16 MFMA, BM=64) ----------------

template <int K, int BN>
struct GemmCfg {
    static constexpr int SB = K + 8;
    static constexpr int CE = BN / 2 + 8;
    static constexpr int SLABSZ = BN * SB;
    static constexpr int EPISZ = 4 * 32 * CE;
    static constexpr int SMEMSZ = SLABSZ > EPISZ ? SLABSZ : EPISZ;   // in f16
};

template <int K, int BN>
__device__ __forceinline__ void gemm_body(
    int bx, int by, f16* __restrict__ smem,
    const f16* __restrict__ A, const f16* __restrict__ Bt,
    const float* __restrict__ biasA, const float* __restrict__ biasB, int NS,
    int M, int relu,
    f16* __restrict__ C1, f16* __restrict__ C2) {
    constexpr int KS = K / 32;
    constexpr int PF = (KS < 8) ? KS : 8;
    constexpr int COLW = BN / 2;
    constexpr int NT = COLW / 16;
    constexpr int SB = GemmCfg<K, BN>::SB;
    constexpr int CE = GemmCfg<K, BN>::CE;

    f16* Bs = smem;
    int tid = threadIdx.x;
    int wave = tid >> 6, lane = tid & 63;
    int quad = lane >> 4, l16 = lane & 15;
    int wr = wave >> 1, wc = wave & 1;
    int row0 = by * 64;
    int col0 = bx * BN;

    constexpr int NCH = BN * K / 8;
#pragma unroll
    for (int i = 0; i < NCH / 256; ++i) {
        int c = tid + i * 256;
        int r = c / (K / 8), ko = (c % (K / 8)) * 8;
        uint4 v = *(const uint4*)&Bt[(size_t)(col0 + r) * K + ko];
        *(uint4*)&Bs[r * SB + ko] = v;
    }
    __syncthreads();

    const f16* Aptr[2];
#pragma unroll
    for (int mt = 0; mt < 2; ++mt) {
        int arow = row0 + wr * 32 + mt * 16 + l16;
        if (arow >= M) arow = M - 1;
        Aptr[mt] = &A[(size_t)arow * K + quad * 8];
    }

    f32x4 acc[2][NT];
#pragma unroll
    for (int mt = 0; mt < 2; ++mt)
#pragma unroll
        for (int j = 0; j < NT; ++j) acc[mt][j] = (f32x4){0.f, 0.f, 0.f, 0.f};

    f16x8 afb[2][PF];
#pragma unroll
    for (int mt = 0; mt < 2; ++mt)
#pragma unroll
        for (int i = 0; i < PF; ++i)
            afb[mt][i] = *(const f16x8*)&Aptr[mt][i * 32];

#pragma unroll
    for (int s = 0; s < KS; ++s) {
        f16x8 af0 = afb[0][s % PF], af1 = afb[1][s % PF];
        if (s + PF < KS) {
            afb[0][s % PF] = *(const f16x8*)&Aptr[0][(s + PF) * 32];
            afb[1][s % PF] = *(const f16x8*)&Aptr[1][(s + PF) * 32];
        }
        const f16* bbase = &Bs[(size_t)(wc * COLW) * SB + s * 32 + quad * 8];
#pragma unroll
        for (int nt = 0; nt < NT; ++nt) {
            f16x8 bf = *(const f16x8*)&bbase[(nt * 16 + l16) * SB];
            acc[0][nt] = __builtin_amdgcn_mfma_f32_16x16x32_f16(af0, bf, acc[0][nt], 0, 0, 0);
            acc[1][nt] = __builtin_amdgcn_mfma_f32_16x16x32_f16(af1, bf, acc[1][nt], 0, 0, 0);
        }
    }

    __syncthreads();
    f16* ep = &smem[wave * 32 * CE];
#pragma unroll
    for (int mt = 0; mt < 2; ++mt)
#pragma unroll
        for (int nt = 0; nt < NT; ++nt) {
            int gcol = col0 + wc * COLW + nt * 16 + l16;
            float bb = (gcol < NS) ? biasA[gcol] : biasB[gcol - NS];
#pragma unroll
            for (int r = 0; r < 4; ++r) {
                float v = acc[mt][nt][r] + bb;
                if (relu) v = fmaxf(v, 0.f);
                ep[(mt * 16 + quad * 4 + r) * CE + nt * 16 + l16] = (f16)v;
            }
        }
    constexpr int CPR = COLW / 8;
    constexpr int NPASS = (32 * CPR) / 64;
#pragma unroll
    for (int i = 0; i < NPASS; ++i) {
        int u = lane + i * 64;
        int row = u / CPR, seg = u % CPR;
        uint4 v = *(const uint4*)&ep[row * CE + seg * 8];
        int grow = row0 + wr * 32 + row;
        int gcol = col0 + wc * COLW + seg * 8;
        if (grow < M) {
            if (gcol < NS) *(uint4*)&C1[(size_t)grow * NS + gcol] = v;
            else           *(uint4*)&C2[(size_t)grow * NS + (gcol - NS)] = v;
        }
    }
}

// ---------------- gather-GEMM: compact rows via wlist (conv2t over W) ----------------

__global__ __launch_bounds__(256) void conv2t_gather_kernel(
    const f16* __restrict__ A, const f16* __restrict__ Bt,
    const float* __restrict__ bias,
    const int* __restrict__ wlist, const int* __restrict__ wcnt,
    f16* __restrict__ C) {
    constexpr int K = 256, BN = 128;
    constexpr int KS = K / 32, PF = 8;
    constexpr int COLW = BN / 2, NT = COLW / 16;
    constexpr int SB = GemmCfg<K, BN>::SB;
    constexpr int CE = GemmCfg<K, BN>::CE;
    __shared__ __align__(16) f16 smem[GemmCfg<K, BN>::SMEMSZ];

    int M_c = wcnt[0];
    int row0 = blockIdx.y * 64;
    if (row0 >= M_c) return;

    f16* Bs = smem;
    int tid = threadIdx.x;
    int wave = tid >> 6, lane = tid & 63;
    int quad = lane >> 4, l16 = lane & 15;
    int wr = wave >> 1, wc = wave & 1;
    int col0 = blockIdx.x * BN;

    constexpr int NCH = BN * K / 8;
#pragma unroll
    for (int i = 0; i < NCH / 256; ++i) {
        int c = tid + i * 256;
        int r = c / (K / 8), ko = (c % (K / 8)) * 8;
        uint4 v = *(const uint4*)&Bt[(size_t)(col0 + r) * K + ko];
        *(uint4*)&Bs[r * SB + ko] = v;
    }
    __syncthreads();

    const f16* Aptr[2];
#pragma unroll
    for (int mt = 0; mt < 2; ++mt) {
        int crow = row0 + wr * 32 + mt * 16 + l16;
        if (crow >= M_c) crow = M_c - 1;
        int arow = wlist[crow];
        Aptr[mt] = &A[(size_t)arow * K + quad * 8];
    }

    f32x4 acc[2][NT];
#pragma unroll
    for (int mt = 0; mt < 2; ++mt)
#pragma unroll
        for (int j = 0; j < NT; ++j) acc[mt][j] = (f32x4){0.f, 0.f, 0.f, 0.f};

    f16x8 afb[2][PF];
#pragma unroll
    for (int mt = 0; mt < 2; ++mt)
#pragma unroll
        for (int i = 0; i < PF; ++i)
            afb[mt][i] = *(const f16x8*)&Aptr[mt][i * 32];

#pragma unroll
    for (int s = 0; s < KS; ++s) {
        f16x8 af0 = afb[0][s % PF], af1 = afb[1][s % PF];
        const f16* bbase = &Bs[(size_t)(wc * COLW) * SB + s * 32 + quad * 8];
#pragma unroll
        for (int nt = 0; nt < NT; ++nt) {
            f16x8 bf = *(const f16x8*)&bbase[(nt * 16 + l16) * SB];
            acc[0][nt] = __builtin_amdgcn_mfma_f32_16x16x32_f16(af0, bf, acc[0][nt], 0, 0, 0);
            acc[1][nt] = __builtin_amdgcn_mfma_f32_16x16x32_f16(af1, bf, acc[1][nt], 0, 0, 0);
        }
    }

    __syncthreads();
    f16* ep = &smem[wave * 32 * CE];
#pragma unroll
    for (int mt = 0; mt < 2; ++mt)
#pragma unroll
        for (int nt = 0; nt < NT; ++nt) {
            int gcol = col0 + wc * COLW + nt * 16 + l16;
            float bb = bias[gcol];
#pragma unroll
            for (int r = 0; r < 4; ++r)
                ep[(mt * 16 + quad * 4 + r) * CE + nt * 16 + l16] =
                    (f16)(acc[mt][nt][r] + bb);
        }
    constexpr int CPR = COLW / 8;
    constexpr int NPASS = (32 * CPR) / 64;
#pragma unroll
    for (int i = 0; i < NPASS; ++i) {
        int u = lane + i * 64;
        int row = u / CPR, seg = u % CPR;
        uint4 v = *(const uint4*)&ep[row * CE + seg * 8];
        int grow = row0 + wr * 32 + row;
        int gcol = col0 + wc * COLW + seg * 8;
        if (grow < M_c) *(uint4*)&C[(size_t)grow * DD + gcol] = v;
    }
}

// ---------------- worklist + edge-list build ----------------

__device__ __forceinline__ void wappend(int src, int* __restrict__ inW,
                                        int* __restrict__ wcnt,
                                        int* __restrict__ wlist,
                                        int* __restrict__ mapv,
                                        int* __restrict__ w_edges,
                                        int* __restrict__ ecnt) {
    if (atomicExch(&inW[src], 1) == 0) {
        int c = atomicAdd(wcnt, 1);
        if (c < WCAP) {
            wlist[c] = src;
            mapv[src] = c;
            w_edges[c * ECAP] = src;   // self-loop seed
            ecnt[c] = 1;
        }
    }
}

// ---------------- merged dispatches ----------------
// enc1 + S0-mark (last block): both depend only on prep_all.
__global__ __launch_bounds__(256) void enc1_s0_kernel(
    const f16* __restrict__ A, const f16* __restrict__ Bt,
    const float* __restrict__ bias, int M, f16* __restrict__ C, int gemmBlocks,
    const int* __restrict__ indices, int B,
    int* __restrict__ s0f, int* __restrict__ inW, int* __restrict__ wcnt,
    int* __restrict__ wlist, int* __restrict__ mapv,
    int* __restrict__ w_edges, int* __restrict__ ecnt) {
    __shared__ __align__(16) f16 smem[GemmCfg<64, 128>::SMEMSZ];
    int bid = blockIdx.x;
    if (bid >= gemmBlocks) {                   // S0 mark + seed worklist
        int t = threadIdx.x;
        if (t < B) {
            int src = indices[t];
            s0f[src] = 1;
            wappend(src, inW, wcnt, wlist, mapv, w_edges, ecnt);
        }
        return;
    }
    gemm_body<64, 128>(bid & 3, bid >> 2, smem, A, Bt, bias, bias, 512, M, 1, C, C);
}

// enc2 + W-scan: enc2 needs enc1; W-scan needs S0 marks.
__global__ __launch_bounds__(256) void enc2_wscan_kernel(
    const f16* __restrict__ A, const f16* __restrict__ Bt,
    const float* __restrict__ bias, int M, f16* __restrict__ C, int gemmBlocks,
    const int* __restrict__ ei, int E,
    const int* __restrict__ s0f, int* __restrict__ inW, int* __restrict__ wcnt,
    int* __restrict__ wlist, int* __restrict__ mapv,
    int* __restrict__ w_edges, int* __restrict__ ecnt) {
    __shared__ __align__(16) f16 smem[GemmCfg<512, 64>::SMEMSZ];
    int bid = blockIdx.x;
    if (bid < gemmBlocks) {
        gemm_body<512, 64>(0, bid, smem, A, Bt, bias, bias, 64, M, 1, C, C);
    } else {                                   // W scan over original E edges
        int e = (bid - gemmBlocks) * 256 + threadIdx.x;
        if (e < E) {
            int dst = ei[E + e];
            if (s0f[dst])
                wappend(ei[e], inW, wcnt, wlist, mapv, w_edges, ecnt);
        }
    }
}

// conv1t + W edge-list build: conv1t needs enc2; ebuild needs inW/mapv (complete).
__global__ __launch_bounds__(256) void conv1t_ebuild_kernel(
    const f16* __restrict__ A, const f16* __restrict__ Bt,
    const float* __restrict__ biasA, const float* __restrict__ biasB, int M,
    f16* __restrict__ C1, f16* __restrict__ C2, int gemmBlocks,
    const int* __restrict__ ei, int E,
    const int* __restrict__ inW, const int* __restrict__ mapv,
    int* __restrict__ w_edges, int* __restrict__ ecnt) {
    __shared__ __align__(16) f16 smem[GemmCfg<64, 128>::SMEMSZ];
    int bid = blockIdx.x;
    if (bid < gemmBlocks) {
        gemm_body<64, 128>(bid & 3, bid >> 2, smem, A, Bt, biasA, biasB, DD, M, 0, C1, C2);
    } else {
        int e = (bid - gemmBlocks) * 256 + threadIdx.x;
        if (e < E) {
            int dst = ei[E + e];
            if (inW[dst]) {
                int c = mapv[dst];
                int pos = atomicAdd(&ecnt[c], 1);
                if (pos < ECAP) w_edges[c * ECAP + pos] = ei[e];
            }
        }
    }
}

// ---------------- fused GATv2 layer 1: 1 W-node/wave, compact edge lists ----------------

__global__ __launch_bounds__(256) void gat_fused_kernel(
    const uint4* __restrict__ xl, const uint4* __restrict__ xr,
    const float4* __restrict__ att,
    const int* __restrict__ wlist, const int* __restrict__ wcnt,
    const int* __restrict__ w_edges, const int* __restrict__ ecnt,
    const float4* __restrict__ bias, uint4* __restrict__ h16) {
    int w = (blockIdx.x * blockDim.x + threadIdx.x) >> 6;
    int lane = threadIdx.x & 63;
    int half = lane >> 5, l32 = lane & 31;
    if (w >= wcnt[0]) return;
    int node = wlist[w];
    int L = ecnt[w];
    if (L > ECAP) L = ECAP;
    const int* elist = &w_edges[w * ECAP];
    uint4 xrw = xr[(size_t)node * 32 + l32];
    f16x2 xr0 = u2h(xrw.x), xr1 = u2h(xrw.y), xr2 = u2h(xrw.z), xr3 = u2h(xrw.w);
    float4 awA = att[l32 * 2], awB = att[l32 * 2 + 1];
    f16x2 a6[4] = {{(f16)(0.6f * awA.x), (f16)(0.6f * awA.y)},
                   {(f16)(0.6f * awA.z), (f16)(0.6f * awA.w)},
                   {(f16)(0.6f * awB.x), (f16)(0.6f * awB.y)},
                   {(f16)(0.6f * awB.z), (f16)(0.6f * awB.w)}};
    f16x2 a4[4] = {{(f16)(0.4f * awA.x), (f16)(0.4f * awA.y)},
                   {(f16)(0.4f * awA.z), (f16)(0.4f * awA.w)},
                   {(f16)(0.4f * awB.x), (f16)(0.4f * awB.y)},
                   {(f16)(0.4f * awB.z), (f16)(0.4f * awB.w)}};
    float denom = 0.f;
    float acc0 = 0.f, acc1 = 0.f, acc2 = 0.f, acc3 = 0.f;
    float acc4 = 0.f, acc5 = 0.f, acc6 = 0.f, acc7 = 0.f;

    auto edge_dot = [&](uint4 raw) -> float {
        f16x2 t0 = u2h(raw.x) + xr0, t1 = u2h(raw.y) + xr1;
        f16x2 t2 = u2h(raw.z) + xr2, t3 = u2h(raw.w) + xr3;
        float d = __builtin_amdgcn_fdot2(t0, a6[0], 0.f, false);
        d = __builtin_amdgcn_fdot2(u2h(h2u(t0) & 0x7FFF7FFFu), a4[0], d, false);
        d = __builtin_amdgcn_fdot2(t1, a6[1], d, false);
        d = __builtin_amdgcn_fdot2(u2h(h2u(t1) & 0x7FFF7FFFu), a4[1], d, false);
        d = __builtin_amdgcn_fdot2(t2, a6[2], d, false);
        d = __builtin_amdgcn_fdot2(u2h(h2u(t2) & 0x7FFF7FFFu), a4[2], d, false);
        d = __builtin_amdgcn_fdot2(t3, a6[3], d, false);
        d = __builtin_amdgcn_fdot2(u2h(h2u(t3) & 0x7FFF7FFFu), a4[3], d, false);
        return d;
    };
    auto accum = [&](uint4 raw, float ee) {
        f16x2 v0 = u2h(raw.x), v1 = u2h(raw.y), v2 = u2h(raw.z), v3 = u2h(raw.w);
        acc0 = fmaf(ee, (float)v0.x, acc0); acc1 = fmaf(ee, (float)v0.y, acc1);
        acc2 = fmaf(ee, (float)v1.x, acc2); acc3 = fmaf(ee, (float)v1.y, acc3);
        acc4 = fmaf(ee, (float)v2.x, acc4); acc5 = fmaf(ee, (float)v2.y, acc5);
        acc6 = fmaf(ee, (float)v3.x, acc6); acc7 = fmaf(ee, (float)v3.y, acc7);
    };

    int p = half;   // this half's first edge; halves interleave stride 2
    for (; p + 6 < L; p += 8) {
        uint4 raw[4];
#pragma unroll
        for (int j = 0; j < 4; ++j)
            raw[j] = xl[(size_t)elist[p + j * 2] * 32 + l32];
        float sc[4];
#pragma unroll
        for (int j = 0; j < 4; ++j) sc[j] = edge_dot(raw[j]);
#pragma unroll
        for (int j = 0; j < 4; ++j) sc[j] += __shfl_xor(sc[j], 1);
#pragma unroll
        for (int j = 0; j < 4; ++j) sc[j] += __shfl_xor(sc[j], 2);
#pragma unroll
        for (int j = 0; j < 4; ++j) sc[j] += __shfl_xor(sc[j], 4);
#pragma unroll
        for (int j = 0; j < 4; ++j) {
            float ee = __expf(sc[j]);
            denom += ee;
            accum(raw[j], ee);
        }
    }
    for (; p < L; p += 2) {
        uint4 raw = xl[(size_t)elist[p] * 32 + l32];
        float d = edge_dot(raw);
        d += __shfl_xor(d, 1);
        d += __shfl_xor(d, 2);
        d += __shfl_xor(d, 4);
        float ee = __expf(d);
        denom += ee;
        accum(raw, ee);
    }
    // combine halves
    denom += __shfl_xor(denom, 32);
    acc0 += __shfl_xor(acc0, 32); acc1 += __shfl_xor(acc1, 32);
    acc2 += __shfl_xor(acc2, 32); acc3 += __shfl_xor(acc3, 32);
    acc4 += __shfl_xor(acc4, 32); acc5 += __shfl_xor(acc5, 32);
    acc6 += __shfl_xor(acc6, 32); acc7 += __shfl_xor(acc7, 32);

    if (half == 0) {
        float inv = 1.f / (denom + 1e-16f);
        float4 bbA = bias[l32 * 2], bbB = bias[l32 * 2 + 1];
        float o0 = fmaxf(fmaf(acc0, inv, bbA.x), 0.f);
        float o1 = fmaxf(fmaf(acc1, inv, bbA.y), 0.f);
        float o2 = fmaxf(fmaf(acc2, inv, bbA.z), 0.f);
        float o3 = fmaxf(fmaf(acc3, inv, bbA.w), 0.f);
        float o4 = fmaxf(fmaf(acc4, inv, bbB.x), 0.f);
        float o5 = fmaxf(fmaf(acc5, inv, bbB.y), 0.f);
        float o6 = fmaxf(fmaf(acc6, inv, bbB.z), 0.f);
        float o7 = fmaxf(fmaf(acc7, inv, bbB.w), 0.f);
        f16x2 h0 = {(f16)o0, (f16)o1}, h1 = {(f16)o2, (f16)o3};
        f16x2 h2 = {(f16)o4, (f16)o5}, h3 = {(f16)o6, (f16)o7};
        uint4 outw = make_uint4(h2u(h0), h2u(h1), h2u(h2), h2u(h3));
        h16[(size_t)node * 32 + l32] = outw;
    }
}

// ---------------- fused GAT2 (indexed) + dueling head, 1024 threads / batch elem ----------------
// xl rows are COMPACT (conv2t_gather output); node's edge list at mapv[node].

__global__ __launch_bounds__(1024) void gat2_head_kernel(
    const uint4* __restrict__ xl, const f16* __restrict__ hC1,
    const f16* __restrict__ wr2nt, const float* __restrict__ br2,
    const float4* __restrict__ att,
    const int* __restrict__ indices, const int* __restrict__ mapv,
    const int* __restrict__ w_edges, const int* __restrict__ ecnt,
    const float* __restrict__ bias2, const f16* __restrict__ hE16,
    const float* __restrict__ qw1, const float* __restrict__ qb1,
    const float* __restrict__ qw2, const float* __restrict__ qb2,
    const float* __restrict__ vw1, const float* __restrict__ vb1,
    const float* __restrict__ vw2, const float* __restrict__ vb2,
    float* __restrict__ out) {
    __shared__ float feat[576];
    __shared__ float xrs[256];
    __shared__ float partial[4][256];
    __shared__ float pden[16][32];
    __shared__ float pacc[16][32][8];
    __shared__ float red[384];
    int b = blockIdx.x;
    int t = threadIdx.x;
    int wave = t >> 6, lane = t & 63;
    int half = lane >> 5, l32 = lane & 31;
    int node = indices[b];

    // ---- phase 0: feat[0..320) ----
    if (t < 320) {
        feat[t] = (t < 64) ? (float)hE16[(size_t)node * 64 + t]
                           : (float)hC1[(size_t)node * 256 + t - 64];
    }
    __syncthreads();

    // ---- phase 1: xr (coalesced, k-quartered) ----
    {
        int o = t & 255, kq = t >> 8;
        const f16* w = &wr2nt[(size_t)(kq * 64) * 256 + o];
        const float* f = &feat[64 + kq * 64];
        float a0 = 0.f, a1 = 0.f;
#pragma unroll
        for (int k = 0; k < 64; k += 2) {
            a0 = fmaf(f[k],     (float)w[(size_t)k * 256],       a0);
            a1 = fmaf(f[k + 1], (float)w[(size_t)(k + 1) * 256], a1);
        }
        partial[kq][o] = a0 + a1;
    }
    __syncthreads();
    if (t < 256)
        xrs[t] = partial[0][t] + partial[1][t] + partial[2][t] + partial[3][t] + br2[t];
    __syncthreads();

    f16x2 xr0 = {(f16)xrs[l32 * 8 + 0], (f16)xrs[l32 * 8 + 1]};
    f16x2 xr1 = {(f16)xrs[l32 * 8 + 2], (f16)xrs[l32 * 8 + 3]};
    f16x2 xr2 = {(f16)xrs[l32 * 8 + 4], (f16)xrs[l32 * 8 + 5]};
    f16x2 xr3 = {(f16)xrs[l32 * 8 + 6], (f16)xrs[l32 * 8 + 7]};

    // ---- phase 2: GAT edge loop, 32-way slice split ----
    int cidx0 = mapv[node];
    int L = ecnt[cidx0];
    if (L > ECAP) L = ECAP;
    const int* elist = &w_edges[cidx0 * ECAP];
    float4 awA = att[l32 * 2], awB = att[l32 * 2 + 1];
    f16x2 a6[4] = {{(f16)(0.6f * awA.x), (f16)(0.6f * awA.y)},
                   {(f16)(0.6f * awA.z), (f16)(0.6f * awA.w)},
                   {(f16)(0.6f * awB.x), (f16)(0.6f * awB.y)},
                   {(f16)(0.6f * awB.z), (f16)(0.6f * awB.w)}};
    f16x2 a4[4] = {{(f16)(0.4f * awA.x), (f16)(0.4f * awA.y)},
                   {(f16)(0.4f * awA.z), (f16)(0.4f * awA.w)},
                   {(f16)(0.4f * awB.x), (f16)(0.4f * awB.y)},
                   {(f16)(0.4f * awB.z), (f16)(0.4f * awB.w)}};
    float denom = 0.f;
    float acc0 = 0.f, acc1 = 0.f, acc2 = 0.f, acc3 = 0.f;
    float acc4 = 0.f, acc5 = 0.f, acc6 = 0.f, acc7 = 0.f;

    auto edge_dot = [&](uint4 raw) -> float {
        f16x2 t0 = u2h(raw.x) + xr0, t1 = u2h(raw.y) + xr1;
        f16x2 t2 = u2h(raw.z) + xr2, t3 = u2h(raw.w) + xr3;
        float d = __builtin_amdgcn_fdot2(t0, a6[0], 0.f, false);
        d = __builtin_amdgcn_fdot2(u2h(h2u(t0) & 0x7FFF7FFFu), a4[0], d, false);
        d = __builtin_amdgcn_fdot2(t1, a6[1], d, false);
        d = __builtin_amdgcn_fdot2(u2h(h2u(t1) & 0x7FFF7FFFu), a4[1], d, false);
        d = __builtin_amdgcn_fdot2(t2, a6[2], d, false);
        d = __builtin_amdgcn_fdot2(u2h(h2u(t2) & 0x7FFF7FFFu), a4[2], d, false);
        d = __builtin_amdgcn_fdot2(t3, a6[3], d, false);
        d = __builtin_amdgcn_fdot2(u2h(h2u(t3) & 0x7FFF7FFFu), a4[3], d, false);
        return d;
    };
    auto accum = [&](uint4 raw, float ee) {
        f16x2 v0 = u2h(raw.x), v1 = u2h(raw.y), v2 = u2h(raw.z), v3 = u2h(raw.w);
        acc0 = fmaf(ee, (float)v0.x, acc0); acc1 = fmaf(ee, (float)v0.y, acc1);
        acc2 = fmaf(ee, (float)v1.x, acc2); acc3 = fmaf(ee, (float)v1.y, acc3);
        acc4 = fmaf(ee, (float)v2.x, acc4); acc5 = fmaf(ee, (float)v2.y, acc5);
        acc6 = fmaf(ee, (float)v3.x, acc6); acc7 = fmaf(ee, (float)v3.y, acc7);
    };

    for (int p = (wave << 1) + half; p < L; p += 32) {
        int cidx = mapv[elist[p]];
        uint4 raw = xl[(size_t)cidx * 32 + l32];
        float d = edge_dot(raw);
        d += __shfl_xor(d, 1);
        d += __shfl_xor(d, 2);
        d += __shfl_xor(d, 4);
        float ee = __expf(d);
        denom += ee;
        accum(raw, ee);
    }
    denom += __shfl_xor(denom, 32);
    acc0 += __shfl_xor(acc0, 32); acc1 += __shfl_xor(acc1, 32);
    acc2 += __shfl_xor(acc2, 32); acc3 += __shfl_xor(acc3, 32);
    acc4 += __shfl_xor(acc4, 32); acc5 += __shfl_xor(acc5, 32);
    acc6 += __shfl_xor(acc6, 32); acc7 += __shfl_xor(acc7, 32);
    if (half == 0) {
        pden[wave][l32] = denom;
        pacc[wave][l32][0] = acc0; pacc[wave][l32][1] = acc1;
        pacc[wave][l32][2] = acc2; pacc[wave][l32][3] = acc3;
        pacc[wave][l32][4] = acc4; pacc[wave][l32][5] = acc5;
        pacc[wave][l32][6] = acc6; pacc[wave][l32][7] = acc7;
    }
    __syncthreads();

    if (t < 256) {
        int lw = t >> 3, d = t & 7;
        float den = 0.f, a = 0.f;
#pragma unroll
        for (int w = 0; w < 16; ++w) { den += pden[w][lw]; a += pacc[w][lw][d]; }
        float inv = 1.f / (den + 1e-16f);
        feat[320 + t] = fmaxf(fmaf(a, inv, bias2[t]), 0.f);
    }
    __syncthreads();

    // ---- phase 3: dueling head, (o, k-quarter) decomposition ----
    {
        int o = t & 255, kq = t >> 8;
        int k0 = kq * 144;
        float a0 = 0.f, a1 = 0.f;
        if (o < 128) {
            const float* w = &qw1[(size_t)k0 * 128 + o];
            const float* f = &feat[k0];
#pragma unroll
            for (int k = 0; k < 144; k += 2) {
                a0 = fmaf(f[k],     w[(size_t)k * 128],       a0);
                a1 = fmaf(f[k + 1], w[(size_t)(k + 1) * 128], a1);
            }
        } else {
            const float* w = &vw1[(size_t)k0 * 128 + (o - 128)];
            const float* f = &feat[k0];
#pragma unroll
            for (int k = 0; k < 144; k += 2) {
                a0 = fmaf(f[k],     w[(size_t)k * 128],       a0);
                a1 = fmaf(f[k + 1], w[(size_t)(k + 1) * 128], a1);
            }
        }
        partial[kq][o] = a0 + a1;
    }
    __syncthreads();
    if (t < 256) {
        float s4 = partial[0][t] + partial[1][t] + partial[2][t] + partial[3][t];
        if (t < 128) {
            float aq = fmaxf(s4 + qb1[t], 0.f);
            red[t]       = aq * qw2[t * 2 + 0];
            red[128 + t] = aq * qw2[t * 2 + 1];
        } else {
            int tv = t - 128;
            float av = fmaxf(s4 + vb1[tv], 0.f);
            red[256 + tv] = av * vw2[tv];
        }
    }
    __syncthreads();
    for (int s2 = 64; s2 > 0; s2 >>= 1) {
        if (t < s2) {
            red[t] += red[t + s2];
            red[128 + t] += red[128 + t + s2];
            red[256 + t] += red[256 + t + s2];
        }
        __syncthreads();
    }
    if (t == 0) {
        float q0 = red[0] + qb2[0];
        float q1 = red[128] + qb2[1];
        float v  = red[256] + vb2[0];
        float mean = 0.5f * (q0 + q1);
        out[b * 2 + 0] = q0 - mean + v;
        out[b * 2 + 1] = q1 - mean + v;
    }
}

// ---------------- launch ----------------

extern "C" void kernel_launch(void* const* d_in, const int* in_sizes, int n_in,
                              void* d_out, int out_size, void* d_ws, size_t ws_size,
                              hipStream_t stream) {
    const float* x      = (const float*)d_in[0];
    const int*   ei     = (const int*)d_in[1];
    const int*   indices= (const int*)d_in[2];
    const float* enc_w1 = (const float*)d_in[3];
    const float* enc_b1 = (const float*)d_in[4];
    const float* enc_w2 = (const float*)d_in[5];
    const float* enc_b2 = (const float*)d_in[6];
    const float* wl1    = (const float*)d_in[7];
    const float* bl1    = (const float*)d_in[8];
    const float* wr1    = (const float*)d_in[9];
    const float* br1    = (const float*)d_in[10];
    const float* att1   = (const float*)d_in[11];
    const float* bias1  = (const float*)d_in[12];
    const float* wl2    = (const float*)d_in[13];
    const float* bl2    = (const float*)d_in[14];
    const float* wr2    = (const float*)d_in[15];
    const float* br2    = (const float*)d_in[16];
    const float* att2   = (const float*)d_in[17];
    const float* bias2  = (const float*)d_in[18];
    const float* qw1    = (const float*)d_in[19];
    const float* qb1    = (const float*)d_in[20];
    const float* qw2    = (const float*)d_in[21];
    const float* qb2    = (const float*)d_in[22];
    const float* vw1    = (const float*)d_in[23];
    const float* vb1    = (const float*)d_in[24];
    const float* vw2    = (const float*)d_in[25];
    const float* vb2    = (const float*)d_in[26];

    const int N = in_sizes[0] / IN_DIM;
    const int E = in_sizes[1] / 2;
    const int B = in_sizes[2];

    // ---- workspace arena ----
    char* wsb = (char*)d_ws;
    size_t off = 0;
    auto alloc = [&](size_t bytes) -> void* {
        void* p = wsb + off;
        off = (off + bytes + 255) & ~(size_t)255;
        return p;
    };
    f16* x16     = (f16*)alloc((size_t)N * 64 * 2);
    f16* h1_16   = (f16*)alloc((size_t)N * 512 * 2);
    f16* hE16    = (f16*)alloc((size_t)N * 64 * 2);
    f16* xl16    = (f16*)alloc((size_t)N * 256 * 2);
    f16* xr16    = (f16*)alloc((size_t)N * 256 * 2);
    f16* hC1_16  = (f16*)alloc((size_t)N * 256 * 2);
    f16* w1t     = (f16*)alloc((size_t)ENC_H * IN_DIM * 2);
    f16* w2t     = (f16*)alloc((size_t)HID * ENC_H * 2);
    f16* wcat1   = (f16*)alloc((size_t)512 * HID * 2);
    f16* wcat2   = (f16*)alloc((size_t)256 * DD * 2);
    f16* wr2nt   = (f16*)alloc((size_t)DD * DD * 2);
    int* zeros   = (int*)alloc((size_t)(2 * N + 16) * 4);
    int* s0f     = zeros;                 // N
    int* inW     = s0f + N;               // N
    int* wcnt    = inW + N;               // 16
    int* wlist   = (int*)alloc((size_t)WCAP * 4);
    int* mapv    = (int*)alloc((size_t)N * 4);
    int* ecnt    = (int*)alloc((size_t)WCAP * 4);
    int* w_edges = (int*)alloc((size_t)WCAP * ECAP * 4);

    // ---- D1: prep (casts, weight transposes, zero flags) ----
    int nx4 = N * 16;
    int nz = 2 * N + 16;
    int ntot = nx4 + 229376 + nz;
    prep_all<<<(ntot + 255) / 256, 256, 0, stream>>>(
        (const float4*)x, (f16x4*)x16, nx4,
        enc_w1, enc_w2, wl1, wr1, wl2, wr2,
        w1t, w2t, wcat1, wcat2, wr2nt, zeros, nz);

    int grows = (N + 63) / 64;          // 313
    int gemmB1 = 4 * grows;             // 1252
    int escanB = (E + 255) / 256;

    // ---- D2: enc1 + S0 mark/seed ----
    enc1_s0_kernel<<<gemmB1 + 1, 256, 0, stream>>>(
        x16, w1t, enc_b1, N, h1_16, gemmB1,
        indices, B, s0f, inW, wcnt, wlist, mapv, w_edges, ecnt);

    // ---- D3: enc2 + W scan ----
    enc2_wscan_kernel<<<grows + escanB, 256, 0, stream>>>(
        h1_16, w2t, enc_b2, N, hE16, grows,
        ei, E, s0f, inW, wcnt, wlist, mapv, w_edges, ecnt);

    // ---- D4: conv1 transform + W edge-list build ----
    conv1t_ebuild_kernel<<<gemmB1 + escanB, 256, 0, stream>>>(
        hE16, wcat1, bl1, br1, N, xl16, xr16, gemmB1,
        ei, E, inW, mapv, w_edges, ecnt);

    // ---- D5: GAT 1 over W (compact edge lists) ----
    gat_fused_kernel<<<(WCAP * 64) / 256, 256, 0, stream>>>(
        (const uint4*)xl16, (const uint4*)xr16, (const float4*)att1,
        wlist, wcnt, w_edges, ecnt, (const float4*)bias1, (uint4*)hC1_16);

    // ---- D6: conv2 transform, xl half, gathered over W rows (compact out) ----
    conv2t_gather_kernel<<<dim3(2, WCAP / 64), dim3(256), 0, stream>>>(
        hC1_16, wcat2, bl2, wlist, wcnt, xl16);

    // ---- D7: GAT 2 (indexed) + dueling head, fused, 1024 threads ----
    gat2_head_kernel<<<B, 1024, 0, stream>>>(
        (const uint4*)xl16, hC1_16, wr2nt, br2, (const float4*)att2,
        indices, mapv, w_edges, ecnt, bias2, hE16,
        qw1, qb1, qw2, qb2, vw1, vb1, vw2, vb2, (float*)d_out);
}